// Round 8
// baseline (191.368 us; speedup 1.0000x reference)
//
#include <hip/hip_runtime.h>
#include <math.h>

// R7 structure with the spill fixed:
//  - chunk loop is '#pragma unroll 1' (serial): staging registers are REUSED
//    across chunks, so live set == R6's single-chunk kernel (no scratch).
//    R7's full unroll let the scheduler hoist 40 dwordx4 staging loads ->
//    ~160 VGPR demand -> 340 MB scratch spill -> 160us. (Counter-verified.)
//  - LDS padded [16][65]: 520B row stride spreads the reduce-scatter writes
//    across banks (R7's 512B stride put all 8 s-lanes on one bank: 700K
//    conflicts).
//  - Each block: 2 chunks of 32 items streamed serially, ONE barrier, then
//    phase 2 with 64 active lanes (1 item/lane).
// All math fp64 (Cantor chain amplifies seed error ~3^8).

typedef float f32x4 __attribute__((ext_vector_type(4)));

__device__ __forceinline__ constexpr int gidx(int i, int j) {
    return i * 5 - i * (i - 1) / 2 + (j - i);   // upper-tri (i<=j) -> [0,15)
}

__global__ __launch_bounds__(256, 4) void fingerprint_kernel(
    const float* __restrict__ pent, float* __restrict__ out, int nItems)
{
    __shared__ double lds_g[16][65];   // padded: stride 520B, conflict-free

    const int tid  = threadIdx.x;
    const int wave = tid >> 6;
    const int lane = tid & 63;
    const int grp  = lane >> 3;   // group (item) within wave
    const int s    = lane & 7;    // slice within item
    // Gram indices this lane owns after reduce-scatter:
    const int k = ((s & 1) << 3) | ((s & 2) << 1) | ((s & 4) >> 1);

    const long base = (long)blockIdx.x * 64;

#pragma unroll 1
    for (int c = 0; c < 2; ++c) {
        const int slot = c * 32 + wave * 8 + grp;
        long item  = base + slot;
        long itemC = item < nItems ? item : (long)nItems - 1;

        const f32x4* __restrict__ p =
            reinterpret_cast<const f32x4*>(pent + itemC * 640L);

        // 20 x global_load_dwordx4 nt; lanes s=0..7 cover a contiguous 128B
        // chunk per (v,j) -> fully coalesced; stream read once, skip caches.
        f32x4 f[5][4];
#pragma unroll
        for (int v = 0; v < 5; ++v)
#pragma unroll
            for (int j = 0; j < 4; ++j)
                f[v][j] = __builtin_nontemporal_load(&p[v * 32 + j * 8 + s]);

        const float* fp = reinterpret_cast<const float*>(f);

        double g[16];
#pragma unroll
        for (int q = 0; q < 16; ++q) g[q] = 0.0;

#pragma unroll
        for (int t = 0; t < 16; ++t) {       // this lane's 16 dims
            double a[5];
#pragma unroll
            for (int v = 0; v < 5; ++v)
                a[v] = (double)fp[v * 16 + t];
            int q = 0;
#pragma unroll
            for (int i = 0; i < 5; ++i)
#pragma unroll
                for (int j = i; j < 5; ++j) {
                    g[q] = fma(a[i], a[j], g[q]);
                    ++q;
                }
        }

        // 3-stage reduce-scatter within the 8-lane group (masks 1,2,4).
        // Lane-dependent choice on VALUES only; indices static.
        {
            const bool b = (s & 1) != 0;
#pragma unroll
            for (int i = 0; i < 8; ++i) {
                double lo = g[i], hi = g[i + 8];
                double recv = __shfl_xor(b ? lo : hi, 1, 64);
                g[i] = (b ? hi : lo) + recv;
            }
        }
        {
            const bool b = (s & 2) != 0;
#pragma unroll
            for (int i = 0; i < 4; ++i) {
                double lo = g[i], hi = g[i + 4];
                double recv = __shfl_xor(b ? lo : hi, 2, 64);
                g[i] = (b ? hi : lo) + recv;
            }
        }
        {
            const bool b = (s & 4) != 0;
#pragma unroll
            for (int i = 0; i < 2; ++i) {
                double lo = g[i], hi = g[i + 2];
                double recv = __shfl_xor(b ? lo : hi, 4, 64);
                g[i] = (b ? hi : lo) + recv;
            }
        }
        // lane owns sums {k, k+1} in g[0], g[1]; park in LDS (all lanes).
        lds_g[k][slot]     = g[0];
        lds_g[k + 1][slot] = g[1];
    }

    __syncthreads();

    // ---- Phase 2: 64 active lanes, one item per lane ----
    if (tid < 64) {
        const long item2 = base + tid;

        double h[15];
#pragma unroll
        for (int q = 0; q < 15; ++q) h[q] = lds_g[q][tid];

        // Edge statistics over the 10 pairwise distances (ddof=1).
        double e[10];
        double se = 0.0;
        {
            int q = 0;
#pragma unroll
            for (int i = 0; i < 5; ++i)
#pragma unroll
                for (int j = i + 1; j < 5; ++j) {
                    double d2 = fma(-2.0, h[gidx(i, j)],
                                    h[gidx(i, i)] + h[gidx(j, j)]);
                    e[q] = sqrt(d2);
                    se += e[q];
                    ++q;
                }
        }
        double meanE = se * 0.1;
        double ve = 0.0;
#pragma unroll
        for (int q = 0; q < 10; ++q) {
            double d = e[q] - meanE;
            ve = fma(d, d, ve);
        }
        double stdE = sqrt(ve / 9.0);

        // Row sums S[i] = sum_j G[i][j], total T.
        double S[5], T = 0.0;
#pragma unroll
        for (int i = 0; i < 5; ++i) {
            double si = 0.0;
#pragma unroll
            for (int j = 0; j < 5; ++j) {
                int a = i < j ? i : j;
                int b = i < j ? j : i;
                si += h[gidx(a, b)];
            }
            S[i] = si;
            T += si;
        }

        // Vertex spread (ddof=1 over 5 centroid distances).
        double scd = 0.0, cd[5];
#pragma unroll
        for (int v = 0; v < 5; ++v) {
            double c2 = fma(-0.4, S[v], h[gidx(v, v)]) + 0.04 * T;
            cd[v] = (c2 > 0.0) ? sqrt(c2) : 0.0;
            scd += cd[v];
        }
        double meanC = scd * 0.2;
        double vc = 0.0;
#pragma unroll
        for (int v = 0; v < 5; ++v) {
            double d = cd[v] - meanC;
            vc = fma(d, d, vc);
        }
        double spread = sqrt(vc * 0.25);

        // W[pq] = (x_p - x_0)·(x_q - x_0), p,q in 1..4 (PSD) ->
        // det M6 = -16 det W; volume^2 = det W / 576.
        double W[4][4];
#pragma unroll
        for (int pi = 0; pi < 4; ++pi)
#pragma unroll
            for (int qi = 0; qi < 4; ++qi) {
                int lo = (pi < qi ? pi : qi) + 1;
                int hi = (pi < qi ? qi : pi) + 1;
                W[pi][qi] = h[gidx(lo, hi)] - h[gidx(0, qi + 1)]
                          - h[gidx(0, pi + 1)] + h[gidx(0, 0)];
            }

        double det = 1.0;
#pragma unroll
        for (int kk = 0; kk < 4; ++kk) {
            double pv = W[kk][kk];
            det *= pv;
            double inv = (pv != 0.0) ? 1.0 / pv : 0.0;
#pragma unroll
            for (int r = kk + 1; r < 4; ++r) {
                double fac = W[r][kk] * inv;
#pragma unroll
                for (int cc = kk + 1; cc < 4; ++cc)
                    W[r][cc] = fma(-fac, W[kk][cc], W[r][cc]);
            }
        }

        double v2 = det / 576.0;
        double volume = (v2 > 0.0) ? sqrt(v2) : 0.0;

        double vn = 1.0 / (1.0 + exp(-10.0 * volume));
        double er = 1.0 / (1.0 + exp(-(stdE / (meanE + 1e-6))));
        double sn = 1.0 / (1.0 + exp(-spread));

        double seed = 0.4 * vn + 0.3 * er + 0.3 * sn;
        seed = fmin(fmax(seed, 1e-6), 1.0 - 1e-6);
        double drift = (vn + er + sn) * 0.01;

        double x = seed, cv = 0.0, factor = 0.5;
#pragma unroll
        for (int kk = 0; kk < 8; ++kk) {
            double xs = x * 3.0;
            double dg = floor(xs);
            double fr = xs - dg;
            cv += (dg == 2.0) ? factor : 0.0;
            factor *= 0.5;
            x = fmin(fmax(fr + drift, 1e-6), 1.0 - 1e-6);
        }
        cv = fmin(fmax(cv, 0.0), 1.0);

        if (item2 < nItems)
            __builtin_nontemporal_store((float)cv, &out[item2]);
    }
}

extern "C" void kernel_launch(void* const* d_in, const int* in_sizes, int n_in,
                              void* d_out, int out_size, void* d_ws, size_t ws_size,
                              hipStream_t stream) {
    const float* pent = (const float*)d_in[0];
    float* out = (float*)d_out;
    int nItems = in_sizes[0] / 640;            // 5*128 floats per item
    int blocks = (nItems + 63) / 64;           // 64 items per 256-thread block
    hipLaunchKernelGGL(fingerprint_kernel, dim3(blocks), dim3(256), 0, stream,
                       pent, out, nItems);
}

// Round 9
// 147.113 us; speedup vs baseline: 1.3008x; 1.3008x over previous
//
#include <hip/hip_runtime.h>
#include <math.h>

// Tail-amortized R6, loop-free:
//  - TWO chunk bodies instantiated as straight-line code (inlined calls),
//    separated by sched_barrier(0) so the scheduler cannot hoist chunk-2's
//    20 NT staging loads into chunk 1. (R7: full unroll hoisted 40 loads ->
//    spill; R8: a '#pragma unroll 1' LOOP made the allocator clamp to 64
//    VGPR targeting 8 waves/SIMD -> 340MB spill. Counter-verified both.)
//  - Each chunk: 32 items (8/wave), fp64 Gram (15 dots), 3-stage
//    reduce-scatter (14 f64 shuffles), park 2 owned sums/lane in LDS.
//  - ONE __syncthreads, then phase 2 on wave 0: 64 lanes, 1 item/lane.
//  - LDS [16][65] padded (520B stride): 0 bank conflicts (measured R8).
// All math fp64 (Cantor chain amplifies seed error ~3^8).

typedef float f32x4 __attribute__((ext_vector_type(4)));

__device__ __forceinline__ constexpr int gidx(int i, int j) {
    return i * 5 - i * (i - 1) / 2 + (j - i);   // upper-tri (i<=j) -> [0,15)
}

__device__ __forceinline__ void gram_chunk(
    const float* __restrict__ pent, double (*lds_g)[65],
    long base, int slot, int s, int k, int nItems)
{
    long item  = base + slot;
    long itemC = item < nItems ? item : (long)nItems - 1;

    const f32x4* __restrict__ p =
        reinterpret_cast<const f32x4*>(pent + itemC * 640L);

    // 20 x global_load_dwordx4 nt; lanes s=0..7 cover a contiguous 128B
    // chunk per (v,j) -> fully coalesced; stream read once, skip caches.
    f32x4 f[5][4];
#pragma unroll
    for (int v = 0; v < 5; ++v)
#pragma unroll
        for (int j = 0; j < 4; ++j)
            f[v][j] = __builtin_nontemporal_load(&p[v * 32 + j * 8 + s]);

    const float* fp = reinterpret_cast<const float*>(f);

    double g[16];
#pragma unroll
    for (int q = 0; q < 16; ++q) g[q] = 0.0;

#pragma unroll
    for (int t = 0; t < 16; ++t) {       // this lane's 16 dims
        double a[5];
#pragma unroll
        for (int v = 0; v < 5; ++v)
            a[v] = (double)fp[v * 16 + t];
        int q = 0;
#pragma unroll
        for (int i = 0; i < 5; ++i)
#pragma unroll
            for (int j = i; j < 5; ++j) {
                g[q] = fma(a[i], a[j], g[q]);
                ++q;
            }
    }

    // 3-stage reduce-scatter within the 8-lane group (masks 1,2,4).
    // Lane-dependent choice on VALUES only; indices static.
    {
        const bool b = (s & 1) != 0;
#pragma unroll
        for (int i = 0; i < 8; ++i) {
            double lo = g[i], hi = g[i + 8];
            double recv = __shfl_xor(b ? lo : hi, 1, 64);
            g[i] = (b ? hi : lo) + recv;
        }
    }
    {
        const bool b = (s & 2) != 0;
#pragma unroll
        for (int i = 0; i < 4; ++i) {
            double lo = g[i], hi = g[i + 4];
            double recv = __shfl_xor(b ? lo : hi, 2, 64);
            g[i] = (b ? hi : lo) + recv;
        }
    }
    {
        const bool b = (s & 4) != 0;
#pragma unroll
        for (int i = 0; i < 2; ++i) {
            double lo = g[i], hi = g[i + 2];
            double recv = __shfl_xor(b ? lo : hi, 4, 64);
            g[i] = (b ? hi : lo) + recv;
        }
    }
    // lane owns sums {k, k+1}; park in LDS (all 64 lanes write).
    lds_g[k][slot]     = g[0];
    lds_g[k + 1][slot] = g[1];
}

__global__ __launch_bounds__(256, 4) void fingerprint_kernel(
    const float* __restrict__ pent, float* __restrict__ out, int nItems)
{
    __shared__ double lds_g[16][65];   // padded: 520B stride, conflict-free

    const int tid  = threadIdx.x;
    const int wave = tid >> 6;
    const int lane = tid & 63;
    const int grp  = lane >> 3;   // group (item) within wave
    const int s    = lane & 7;    // slice within item
    const int k = ((s & 1) << 3) | ((s & 2) << 1) | ((s & 4) >> 1);

    const long base = (long)blockIdx.x * 64;

    gram_chunk(pent, lds_g, base, 0 * 32 + wave * 8 + grp, s, k, nItems);
    __builtin_amdgcn_sched_barrier(0);   // no cross-chunk hoisting
    gram_chunk(pent, lds_g, base, 1 * 32 + wave * 8 + grp, s, k, nItems);

    __syncthreads();

    // ---- Phase 2: wave 0, one item per lane (64 items) ----
    if (tid < 64) {
        const long item2 = base + tid;

        double h[15];
#pragma unroll
        for (int q = 0; q < 15; ++q) h[q] = lds_g[q][tid];

        // Edge statistics over the 10 pairwise distances (ddof=1).
        double e[10];
        double se = 0.0;
        {
            int q = 0;
#pragma unroll
            for (int i = 0; i < 5; ++i)
#pragma unroll
                for (int j = i + 1; j < 5; ++j) {
                    double d2 = fma(-2.0, h[gidx(i, j)],
                                    h[gidx(i, i)] + h[gidx(j, j)]);
                    e[q] = sqrt(d2);
                    se += e[q];
                    ++q;
                }
        }
        double meanE = se * 0.1;
        double ve = 0.0;
#pragma unroll
        for (int q = 0; q < 10; ++q) {
            double d = e[q] - meanE;
            ve = fma(d, d, ve);
        }
        double stdE = sqrt(ve / 9.0);

        // Row sums S[i] = sum_j G[i][j], total T.
        double S[5], T = 0.0;
#pragma unroll
        for (int i = 0; i < 5; ++i) {
            double si = 0.0;
#pragma unroll
            for (int j = 0; j < 5; ++j) {
                int a = i < j ? i : j;
                int b = i < j ? j : i;
                si += h[gidx(a, b)];
            }
            S[i] = si;
            T += si;
        }

        // Vertex spread (ddof=1 over 5 centroid distances).
        double scd = 0.0, cd[5];
#pragma unroll
        for (int v = 0; v < 5; ++v) {
            double c2 = fma(-0.4, S[v], h[gidx(v, v)]) + 0.04 * T;
            cd[v] = (c2 > 0.0) ? sqrt(c2) : 0.0;
            scd += cd[v];
        }
        double meanC = scd * 0.2;
        double vc = 0.0;
#pragma unroll
        for (int v = 0; v < 5; ++v) {
            double d = cd[v] - meanC;
            vc = fma(d, d, vc);
        }
        double spread = sqrt(vc * 0.25);

        // W[pq] = (x_p - x_0)·(x_q - x_0), p,q in 1..4 (PSD) ->
        // det M6 = -16 det W; volume^2 = det W / 576.
        double W[4][4];
#pragma unroll
        for (int pi = 0; pi < 4; ++pi)
#pragma unroll
            for (int qi = 0; qi < 4; ++qi) {
                int lo = (pi < qi ? pi : qi) + 1;
                int hi = (pi < qi ? qi : pi) + 1;
                W[pi][qi] = h[gidx(lo, hi)] - h[gidx(0, qi + 1)]
                          - h[gidx(0, pi + 1)] + h[gidx(0, 0)];
            }

        double det = 1.0;
#pragma unroll
        for (int kk = 0; kk < 4; ++kk) {
            double pv = W[kk][kk];
            det *= pv;
            double inv = (pv != 0.0) ? 1.0 / pv : 0.0;
#pragma unroll
            for (int r = kk + 1; r < 4; ++r) {
                double fac = W[r][kk] * inv;
#pragma unroll
                for (int cc = kk + 1; cc < 4; ++cc)
                    W[r][cc] = fma(-fac, W[kk][cc], W[r][cc]);
            }
        }

        double v2 = det / 576.0;
        double volume = (v2 > 0.0) ? sqrt(v2) : 0.0;

        double vn = 1.0 / (1.0 + exp(-10.0 * volume));
        double er = 1.0 / (1.0 + exp(-(stdE / (meanE + 1e-6))));
        double sn = 1.0 / (1.0 + exp(-spread));

        double seed = 0.4 * vn + 0.3 * er + 0.3 * sn;
        seed = fmin(fmax(seed, 1e-6), 1.0 - 1e-6);
        double drift = (vn + er + sn) * 0.01;

        double x = seed, cv = 0.0, factor = 0.5;
#pragma unroll
        for (int kk = 0; kk < 8; ++kk) {
            double xs = x * 3.0;
            double dg = floor(xs);
            double fr = xs - dg;
            cv += (dg == 2.0) ? factor : 0.0;
            factor *= 0.5;
            x = fmin(fmax(fr + drift, 1e-6), 1.0 - 1e-6);
        }
        cv = fmin(fmax(cv, 0.0), 1.0);

        if (item2 < nItems)
            __builtin_nontemporal_store((float)cv, &out[item2]);
    }
}

extern "C" void kernel_launch(void* const* d_in, const int* in_sizes, int n_in,
                              void* d_out, int out_size, void* d_ws, size_t ws_size,
                              hipStream_t stream) {
    const float* pent = (const float*)d_in[0];
    float* out = (float*)d_out;
    int nItems = in_sizes[0] / 640;            // 5*128 floats per item
    int blocks = (nItems + 63) / 64;           // 64 items per 256-thread block
    hipLaunchKernelGGL(fingerprint_kernel, dim3(blocks), dim3(256), 0, stream,
                       pent, out, nItems);
}

// Round 10
// 48.583 us; speedup vs baseline: 3.9390x; 3.0281x over previous
//
#include <hip/hip_runtime.h>
#include <math.h>

// Single-wave blocks (64 threads, 8 items, grid 12500):
//  - shortens block duration 4x vs R6 -> end-of-grid drain ~7us -> ~1.8us
//    (R6's measured 5.74 TB/s vs 6.9 fill BW is consistent with a drain of
//    ~one block-duration at the end of the grid).
//  - no __syncthreads, no LDS: reduction + handoff entirely in-register.
//  - per 8-lane group: fp64 Gram (15 dots, 16 dims/lane), 3-stage
//    reduce-scatter (14 f64 shuffles; R9-verified), then 16-shuffle gather
//    so lane s==0 of each group holds all 15 sums; phase 2 on s==0 lanes.
//  - straight-line single body (no chunk loop): avoids the 64-VGPR
//    clamp + 300MB scratch spill that hit R7/R8/R9 (counter-verified).
// All math fp64 (Cantor chain amplifies seed error ~3^8).

typedef float f32x4 __attribute__((ext_vector_type(4)));

__device__ __forceinline__ constexpr int gidx(int i, int j) {
    return i * 5 - i * (i - 1) / 2 + (j - i);   // upper-tri (i<=j) -> [0,15)
}

__global__ __launch_bounds__(64, 4) void fingerprint_kernel(
    const float* __restrict__ pent, float* __restrict__ out, int nItems)
{
    const int lane = threadIdx.x;   // 0..63
    const int grp  = lane >> 3;     // item within wave (0..7)
    const int s    = lane & 7;      // slice within item

    const long item  = (long)blockIdx.x * 8 + grp;
    const long itemC = item < nItems ? item : (long)nItems - 1;

    const f32x4* __restrict__ p =
        reinterpret_cast<const f32x4*>(pent + itemC * 640L);

    // 20 x global_load_dwordx4 nt; per (v,j) instruction lanes s=0..7 cover
    // a contiguous 128B chunk per item -> fully coalesced; read-once stream.
    f32x4 f[5][4];
#pragma unroll
    for (int v = 0; v < 5; ++v)
#pragma unroll
        for (int j = 0; j < 4; ++j)
            f[v][j] = __builtin_nontemporal_load(&p[v * 32 + j * 8 + s]);

    const float* fp = reinterpret_cast<const float*>(f);

    double g[16];
#pragma unroll
    for (int q = 0; q < 16; ++q) g[q] = 0.0;

#pragma unroll
    for (int t = 0; t < 16; ++t) {       // this lane's 16 dims
        double a[5];
#pragma unroll
        for (int v = 0; v < 5; ++v)
            a[v] = (double)fp[v * 16 + t];
        int q = 0;
#pragma unroll
        for (int i = 0; i < 5; ++i)
#pragma unroll
            for (int j = i; j < 5; ++j) {
                g[q] = fma(a[i], a[j], g[q]);
                ++q;
            }
    }

    // 3-stage reduce-scatter within the 8-lane group (masks 1,2,4).
    // Lane-dependent choice on VALUES only; indices static. (R9-verified.)
    {
        const bool b = (s & 1) != 0;
#pragma unroll
        for (int i = 0; i < 8; ++i) {
            double lo = g[i], hi = g[i + 8];
            double recv = __shfl_xor(b ? lo : hi, 1, 64);
            g[i] = (b ? hi : lo) + recv;
        }
    }
    {
        const bool b = (s & 2) != 0;
#pragma unroll
        for (int i = 0; i < 4; ++i) {
            double lo = g[i], hi = g[i + 4];
            double recv = __shfl_xor(b ? lo : hi, 2, 64);
            g[i] = (b ? hi : lo) + recv;
        }
    }
    {
        const bool b = (s & 4) != 0;
#pragma unroll
        for (int i = 0; i < 2; ++i) {
            double lo = g[i], hi = g[i + 2];
            double recv = __shfl_xor(b ? lo : hi, 4, 64);
            g[i] = (b ? hi : lo) + recv;
        }
    }
    // Lane (grp,s) owns sums {k(s), k(s)+1}, k(s)=((s&1)<<3)|((s&2)<<1)|((s&4)>>1).

    // In-wave gather: every lane pulls group-local lane m's owned pair;
    // k(m) table is static: m=0..7 -> {0,8,4,12,2,10,6,14}.
    double h[16];
    {
        constexpr int kt[8] = {0, 8, 4, 12, 2, 10, 6, 14};
        const int gbase = lane & ~7;
#pragma unroll
        for (int m = 0; m < 8; ++m) {
            double v0 = __shfl(g[0], gbase | m, 64);
            double v1 = __shfl(g[1], gbase | m, 64);
            h[kt[m]]     = v0;
            h[kt[m] + 1] = v1;
        }
    }

    // ---- Phase 2: lane s==0 of each group, one item each ----
    if (s == 0 && item < nItems) {
        // Edge statistics over the 10 pairwise distances (ddof=1).
        double e[10];
        double se = 0.0;
        {
            int q = 0;
#pragma unroll
            for (int i = 0; i < 5; ++i)
#pragma unroll
                for (int j = i + 1; j < 5; ++j) {
                    double d2 = fma(-2.0, h[gidx(i, j)],
                                    h[gidx(i, i)] + h[gidx(j, j)]);
                    e[q] = sqrt(d2);
                    se += e[q];
                    ++q;
                }
        }
        double meanE = se * 0.1;
        double ve = 0.0;
#pragma unroll
        for (int q = 0; q < 10; ++q) {
            double d = e[q] - meanE;
            ve = fma(d, d, ve);
        }
        double stdE = sqrt(ve / 9.0);

        // Row sums S[i] = sum_j G[i][j], total T.
        double S[5], T = 0.0;
#pragma unroll
        for (int i = 0; i < 5; ++i) {
            double si = 0.0;
#pragma unroll
            for (int j = 0; j < 5; ++j) {
                int a = i < j ? i : j;
                int b = i < j ? j : i;
                si += h[gidx(a, b)];
            }
            S[i] = si;
            T += si;
        }

        // Vertex spread (ddof=1 over 5 centroid distances).
        double scd = 0.0, cd[5];
#pragma unroll
        for (int v = 0; v < 5; ++v) {
            double c2 = fma(-0.4, S[v], h[gidx(v, v)]) + 0.04 * T;
            cd[v] = (c2 > 0.0) ? sqrt(c2) : 0.0;
            scd += cd[v];
        }
        double meanC = scd * 0.2;
        double vc = 0.0;
#pragma unroll
        for (int v = 0; v < 5; ++v) {
            double d = cd[v] - meanC;
            vc = fma(d, d, vc);
        }
        double spread = sqrt(vc * 0.25);

        // W[pq] = (x_p - x_0)·(x_q - x_0), p,q in 1..4 (PSD) ->
        // det M6 = -16 det W; volume^2 = det W / 576.
        double W[4][4];
#pragma unroll
        for (int pi = 0; pi < 4; ++pi)
#pragma unroll
            for (int qi = 0; qi < 4; ++qi) {
                int lo = (pi < qi ? pi : qi) + 1;
                int hi = (pi < qi ? qi : pi) + 1;
                W[pi][qi] = h[gidx(lo, hi)] - h[gidx(0, qi + 1)]
                          - h[gidx(0, pi + 1)] + h[gidx(0, 0)];
            }

        double det = 1.0;
#pragma unroll
        for (int kk = 0; kk < 4; ++kk) {
            double pv = W[kk][kk];
            det *= pv;
            double inv = (pv != 0.0) ? 1.0 / pv : 0.0;
#pragma unroll
            for (int r = kk + 1; r < 4; ++r) {
                double fac = W[r][kk] * inv;
#pragma unroll
                for (int cc = kk + 1; cc < 4; ++cc)
                    W[r][cc] = fma(-fac, W[kk][cc], W[r][cc]);
            }
        }

        double v2 = det / 576.0;
        double volume = (v2 > 0.0) ? sqrt(v2) : 0.0;

        double vn = 1.0 / (1.0 + exp(-10.0 * volume));
        double er = 1.0 / (1.0 + exp(-(stdE / (meanE + 1e-6))));
        double sn = 1.0 / (1.0 + exp(-spread));

        double seed = 0.4 * vn + 0.3 * er + 0.3 * sn;
        seed = fmin(fmax(seed, 1e-6), 1.0 - 1e-6);
        double drift = (vn + er + sn) * 0.01;

        double x = seed, cv = 0.0, factor = 0.5;
#pragma unroll
        for (int kk = 0; kk < 8; ++kk) {
            double xs = x * 3.0;
            double dg = floor(xs);
            double fr = xs - dg;
            cv += (dg == 2.0) ? factor : 0.0;
            factor *= 0.5;
            x = fmin(fmax(fr + drift, 1e-6), 1.0 - 1e-6);
        }
        cv = fmin(fmax(cv, 0.0), 1.0);

        __builtin_nontemporal_store((float)cv, &out[item]);
    }
}

extern "C" void kernel_launch(void* const* d_in, const int* in_sizes, int n_in,
                              void* d_out, int out_size, void* d_ws, size_t ws_size,
                              hipStream_t stream) {
    const float* pent = (const float*)d_in[0];
    float* out = (float*)d_out;
    int nItems = in_sizes[0] / 640;            // 5*128 floats per item
    int blocks = (nItems + 7) / 8;             // 8 items per 64-thread block
    hipLaunchKernelGGL(fingerprint_kernel, dim3(blocks), dim3(64), 0, stream,
                       pent, out, nItems);
}

// Round 11
// 44.676 us; speedup vs baseline: 4.2835x; 1.0875x over previous
//
#include <hip/hip_runtime.h>
#include <math.h>

// REVERT to R6 (best measured: 44.64us, 5.74 TB/s effective read).
// Session ledger: R4 split/occupancy -> spill; R7/R8/R9 multi-chunk ->
// 64-VGPR allocator clamp + ~300MB scratch spill (counter-verified, all
// three codegen variants); R10 single-wave blocks -> phase-2 amplification
// (48.6us). This structure is the optimum found.
//
// Phase 1: one item per 8-lane group (8 items/wave, 32/block). fp64 Gram
//          accumulation (15 dots), 16 dims/lane, butterfly reduce (1,2,4).
//          Group lane 0 writes g[15] to LDS. Non-temporal staging loads
//          (read-once stream, skip cache allocation): +1% measured.
// Phase 2: ONE wave per block, one item per lane (32 lanes active): reads
//          g[15] from LDS, edge stats, spread, det(W) via 4x4 LU
//          (det M6 = -16 det W, vol^2 = det W/576), sigmoids, Cantor chain.
// All math fp64 (Cantor map amplifies seed error ~3^8; need ~1e-9 seed acc).

typedef float f32x4 __attribute__((ext_vector_type(4)));

__device__ __forceinline__ constexpr int gidx(int i, int j) {
    return i * 5 - i * (i - 1) / 2 + (j - i);   // upper-tri (i<=j) -> [0,15)
}

__global__ __launch_bounds__(256, 4) void fingerprint_kernel(
    const float* __restrict__ pent, float* __restrict__ out, int nItems)
{
    __shared__ double lds_g[32][15];   // 3840 B; stride 120 B

    const int tid  = threadIdx.x;
    const int wave = tid >> 6;
    const int lane = tid & 63;
    const int grp  = lane >> 3;   // which of the wave's 8 items
    const int s    = lane & 7;    // slice within the item

    long item  = (long)blockIdx.x * 32 + (long)wave * 8 + grp;
    long itemC = item < nItems ? item : (long)nItems - 1;

    const f32x4* __restrict__ p =
        reinterpret_cast<const f32x4*>(pent + itemC * 640L);

    // 20 x global_load_dwordx4 (nt); per (v,j) instruction lanes s=0..7 cover
    // a contiguous 128B chunk per item -> fully coalesced.
    f32x4 f[5][4];
#pragma unroll
    for (int v = 0; v < 5; ++v)
#pragma unroll
        for (int j = 0; j < 4; ++j)
            f[v][j] = __builtin_nontemporal_load(&p[v * 32 + j * 8 + s]);

    const float* fp = reinterpret_cast<const float*>(f);

    double g[15];
#pragma unroll
    for (int q = 0; q < 15; ++q) g[q] = 0.0;

#pragma unroll
    for (int t = 0; t < 16; ++t) {           // this lane's 16 dims
        double a[5];
#pragma unroll
        for (int v = 0; v < 5; ++v)
            a[v] = (double)fp[v * 16 + t];
        int q = 0;
#pragma unroll
        for (int i = 0; i < 5; ++i)
#pragma unroll
            for (int j = i; j < 5; ++j) {
                g[q] = fma(a[i], a[j], g[q]);
                ++q;
            }
    }

    // Butterfly reduce within the 8-lane group.
#pragma unroll
    for (int m = 1; m <= 4; m <<= 1)
#pragma unroll
        for (int q = 0; q < 15; ++q) g[q] += __shfl_xor(g[q], m, 64);

    // Hand off to LDS (one writer per group; static q indices only).
    if (s == 0) {
        const int slot = wave * 8 + grp;
#pragma unroll
        for (int q = 0; q < 15; ++q) lds_g[slot][q] = g[q];
    }
    __syncthreads();

    // ---- Phase 2: one wave, one item per lane ----
    if (tid < 32) {
        const long item2 = (long)blockIdx.x * 32 + tid;

        double h[15];
#pragma unroll
        for (int q = 0; q < 15; ++q) h[q] = lds_g[tid][q];

        // Edge statistics over the 10 pairwise distances (ddof=1).
        double e[10];
        double se = 0.0;
        {
            int q = 0;
#pragma unroll
            for (int i = 0; i < 5; ++i)
#pragma unroll
                for (int j = i + 1; j < 5; ++j) {
                    double d2 = fma(-2.0, h[gidx(i, j)],
                                    h[gidx(i, i)] + h[gidx(j, j)]);
                    e[q] = sqrt(d2);
                    se += e[q];
                    ++q;
                }
        }
        double meanE = se * 0.1;
        double ve = 0.0;
#pragma unroll
        for (int q = 0; q < 10; ++q) {
            double d = e[q] - meanE;
            ve = fma(d, d, ve);
        }
        double stdE = sqrt(ve / 9.0);

        // Row sums S[i] = sum_j G[i][j], total T.
        double S[5], T = 0.0;
#pragma unroll
        for (int i = 0; i < 5; ++i) {
            double si = 0.0;
#pragma unroll
            for (int j = 0; j < 5; ++j) {
                int a = i < j ? i : j;
                int b = i < j ? j : i;
                si += h[gidx(a, b)];
            }
            S[i] = si;
            T += si;
        }

        // Vertex spread (ddof=1 over 5 centroid distances).
        double scd = 0.0, cd[5];
#pragma unroll
        for (int v = 0; v < 5; ++v) {
            double c2 = fma(-0.4, S[v], h[gidx(v, v)]) + 0.04 * T;
            cd[v] = (c2 > 0.0) ? sqrt(c2) : 0.0;
            scd += cd[v];
        }
        double meanC = scd * 0.2;
        double vc = 0.0;
#pragma unroll
        for (int v = 0; v < 5; ++v) {
            double d = cd[v] - meanC;
            vc = fma(d, d, vc);
        }
        double spread = sqrt(vc * 0.25);

        // W[pq] = (x_p - x_0)·(x_q - x_0), p,q in 1..4 (PSD) ->
        // det M6 = -16 det W; volume^2 = det W / 576.
        double W[4][4];
#pragma unroll
        for (int pi = 0; pi < 4; ++pi)
#pragma unroll
            for (int qi = 0; qi < 4; ++qi) {
                int lo = (pi < qi ? pi : qi) + 1;
                int hi = (pi < qi ? qi : pi) + 1;
                W[pi][qi] = h[gidx(lo, hi)] - h[gidx(0, qi + 1)]
                          - h[gidx(0, pi + 1)] + h[gidx(0, 0)];
            }

        double det = 1.0;
#pragma unroll
        for (int k = 0; k < 4; ++k) {
            double pv = W[k][k];
            det *= pv;
            double inv = (pv != 0.0) ? 1.0 / pv : 0.0;
#pragma unroll
            for (int r = k + 1; r < 4; ++r) {
                double fac = W[r][k] * inv;
#pragma unroll
                for (int c = k + 1; c < 4; ++c)
                    W[r][c] = fma(-fac, W[k][c], W[r][c]);
            }
        }

        double v2 = det / 576.0;
        double volume = (v2 > 0.0) ? sqrt(v2) : 0.0;

        double vn = 1.0 / (1.0 + exp(-10.0 * volume));
        double er = 1.0 / (1.0 + exp(-(stdE / (meanE + 1e-6))));
        double sn = 1.0 / (1.0 + exp(-spread));

        double seed = 0.4 * vn + 0.3 * er + 0.3 * sn;
        seed = fmin(fmax(seed, 1e-6), 1.0 - 1e-6);
        double drift = (vn + er + sn) * 0.01;

        double x = seed, cv = 0.0, factor = 0.5;
#pragma unroll
        for (int k = 0; k < 8; ++k) {
            double xs = x * 3.0;
            double dg = floor(xs);
            double fr = xs - dg;
            cv += (dg == 2.0) ? factor : 0.0;
            factor *= 0.5;
            x = fmin(fmax(fr + drift, 1e-6), 1.0 - 1e-6);
        }
        cv = fmin(fmax(cv, 0.0), 1.0);

        if (item2 < nItems)
            __builtin_nontemporal_store((float)cv, &out[item2]);
    }
}

extern "C" void kernel_launch(void* const* d_in, const int* in_sizes, int n_in,
                              void* d_out, int out_size, void* d_ws, size_t ws_size,
                              hipStream_t stream) {
    const float* pent = (const float*)d_in[0];
    float* out = (float*)d_out;
    int nItems = in_sizes[0] / 640;            // 5*128 floats per item
    int blocks = (nItems + 31) / 32;           // 32 items per 256-thread block
    hipLaunchKernelGGL(fingerprint_kernel, dim3(blocks), dim3(256), 0, stream,
                       pent, out, nItems);
}